// Round 10
// baseline (389.550 us; speedup 1.0000x reference)
//
#include <hip/hip_runtime.h>
#include <hip/hip_bf16.h>

// RangeLoss: mean((preds - adjusted_target)^2) over 8M x 4 fp32.
// R4/R5 evidence: ~100us regardless of HBM vs L3 residency and regardless of
// per-wave unroll depth -> service-rate pinned at ~2.56 TB/s; VALU 7%,
// occupancy ~65%, 0 bank conflicts.
// R9: 2x2 factorial in ONE launch (within-probe A/B, infra too flaky for
// sequential single-variable experiments):
//   V0 plain grid-stride (anchor)   V1 nontemporal grid-stride
//   V2 plain contiguous-chunk       V3 nontemporal contiguous-chunk
// Each variant writes its own partials region; final reduces V0's region.
// Per-dispatch dur_us from rocprof gives the clean comparison.

#define BLOCK 256
#define GRID 2048
#define CR 0.05f

typedef float f32x4 __attribute__((ext_vector_type(4)));

__device__ __forceinline__ float row_loss(f32x4 p, f32x4 t)
{
    // --- _adjust_target, columns 0 and 1 (sequential semantics) ---
    float t0 = t.x;
    if (fabsf(p.x) < 0.01f && t0 == 0.0f) t0 = p.x;
    if (p.x > 0.99f && p.x < 1.01f && t0 == 1.0f) t0 = p.x;

    float t1 = t.y;
    if (fabsf(p.y) < 0.01f && t1 == 0.0f) t1 = p.y;
    if (p.y > 0.99f && p.y < 1.01f && t1 == 1.0f) t1 = p.y;

    // --- confidence-range override on column 1 (reads adjusted t1) ---
    bool cond_hi  = p.z > 0.9f;
    bool cond_rng = (p.y * (1.0f + CR) > t1) && (p.y * (1.0f - CR) < t1);
    if (cond_hi || cond_rng) t1 = p.y;

    float d0 = p.x - t0;
    float d1 = p.y - t1;
    float d2 = p.z - t.z;
    float d3 = p.w - t.w;
    return d0 * d0 + d1 * d1 + d2 * d2 + d3 * d3;
}

template<bool NT, bool CHUNK>
__global__ __launch_bounds__(BLOCK) void range_loss_partial(
    const f32x4* __restrict__ preds,
    const f32x4* __restrict__ targ,
    float* __restrict__ partials,
    int nrows)
{
    float acc = 0.0f;

    if constexpr (CHUNK) {
        // Each block owns one contiguous extent of rows (~62.5 KB reads).
        const int chunk = (nrows + GRID - 1) / GRID;
        const int base  = blockIdx.x * chunk;
        const int end   = min(base + chunk, nrows);
        for (int i = base + (int)threadIdx.x; i < end; i += BLOCK) {
            f32x4 p, t;
            if constexpr (NT) {
                p = __builtin_nontemporal_load(&preds[i]);
                t = __builtin_nontemporal_load(&targ[i]);
            } else {
                p = preds[i];
                t = targ[i];
            }
            acc += row_loss(p, t);
        }
    } else {
        const int tid = blockIdx.x * BLOCK + threadIdx.x;
        const int stride = GRID * BLOCK;
        for (int i = tid; i < nrows; i += stride) {
            f32x4 p, t;
            if constexpr (NT) {
                p = __builtin_nontemporal_load(&preds[i]);
                t = __builtin_nontemporal_load(&targ[i]);
            } else {
                p = preds[i];
                t = targ[i];
            }
            acc += row_loss(p, t);
        }
    }

    // wave (64-lane) reduction
    for (int off = 32; off > 0; off >>= 1)
        acc += __shfl_down(acc, off);

    __shared__ float smem[BLOCK / 64];
    int lane = threadIdx.x & 63;
    int wave = threadIdx.x >> 6;
    if (lane == 0) smem[wave] = acc;
    __syncthreads();

    if (threadIdx.x == 0) {
        float s = 0.0f;
        #pragma unroll
        for (int w = 0; w < BLOCK / 64; ++w) s += smem[w];
        partials[blockIdx.x] = s;
    }
}

__global__ __launch_bounds__(BLOCK) void range_loss_final(
    const float* __restrict__ partials,
    int nparts,
    float* __restrict__ out,
    double inv_n)
{
    double acc = 0.0;
    for (int i = threadIdx.x; i < nparts; i += BLOCK)
        acc += (double)partials[i];

    for (int off = 32; off > 0; off >>= 1)
        acc += __shfl_down(acc, off);

    __shared__ double smem[BLOCK / 64];
    int lane = threadIdx.x & 63;
    int wave = threadIdx.x >> 6;
    if (lane == 0) smem[wave] = acc;
    __syncthreads();

    if (threadIdx.x == 0) {
        double s = 0.0;
        #pragma unroll
        for (int w = 0; w < BLOCK / 64; ++w) s += smem[w];
        out[0] = (float)(s * inv_n);
    }
}

extern "C" void kernel_launch(void* const* d_in, const int* in_sizes, int n_in,
                              void* d_out, int out_size, void* d_ws, size_t ws_size,
                              hipStream_t stream)
{
    const f32x4* preds = (const f32x4*)d_in[0];
    const f32x4* targ  = (const f32x4*)d_in[1];

    int n_elems = in_sizes[0];     // 32,000,000
    int nrows   = n_elems / 4;     // 8,000,000 rows of float4

    float* part0 = (float*)d_ws;            // 4 x GRID floats = 32 KB scratch
    float* part1 = part0 + GRID;
    float* part2 = part1 + GRID;
    float* part3 = part2 + GRID;
    float* out   = (float*)d_out;

    double inv_n = 1.0 / (double)n_elems;

    // 2x2 factorial, each a full pass; per-dispatch timing via rocprof.
    range_loss_partial<false, false><<<GRID, BLOCK, 0, stream>>>(preds, targ, part0, nrows);
    range_loss_partial<true,  false><<<GRID, BLOCK, 0, stream>>>(preds, targ, part1, nrows);
    range_loss_partial<false, true ><<<GRID, BLOCK, 0, stream>>>(preds, targ, part2, nrows);
    range_loss_partial<true,  true ><<<GRID, BLOCK, 0, stream>>>(preds, targ, part3, nrows);

    // Final reduces the anchor variant's partials (all variants are correct).
    range_loss_final<<<1, BLOCK, 0, stream>>>(part0, GRID, out, inv_n);
}